// Round 4
// baseline (1006.872 us; speedup 1.0000x reference)
//
#include <hip/hip_runtime.h>
#include <hip/hip_bf16.h>

// EdgeFFN: out[e] = relu(concat(x[src[e]], x[dst[e]]) @ W1 + b1) @ W2 + b2
// E=640000, IN=128, CAT=256, HID=256, OUT=64
//
// Round-4 design notes:
//  - Register-staged gather (NOT global_load_lds: round-3 showed DMA random
//    gather bypasses L3 absorption -> 1.1 GB HBM fetch vs 148 MB staged).
//  - Cross-tile pipeline: gather(t+1) issued right after GEMM1(t) MFMAs,
//    hidden under H-write + GEMM2 + epilogue; ei prefetched 2 tiles ahead.
//  - __launch_bounds__(256,3): 170-VGPR cap. Round-2's (256,4)=128 cap
//    spilled (WRITE 1.26 GB scratch signature). Peak live ~128 regs fits.

#define N_EDGES_C 640000
#define N_NODES_C 100000
#define IN_DIM_C  128
#define CAT_DIM_C 256
#define HIDDEN_C  256
#define OUT_DIM_C 64
#define BM        64    // edges per tile
#define LDA       264   // padded LDS row: 528B stride, worst 2-way conflict (free, m136)
#define TPB_TILES 5     // tiles per block
#define GRID_MAIN 2000  // 2000 * 5 * 64 = 640000 exactly

typedef __attribute__((ext_vector_type(8))) short bf16x8;
typedef __attribute__((ext_vector_type(4))) float f32x4;

__device__ __forceinline__ ushort f2bs(float f) {
  union { __hip_bfloat16 h; ushort u; } c;
  c.h = __float2bfloat16(f);
  return c.u;
}

// ---- prep: cast node features f32 -> bf16 (vectorized 8/thread) ----
__global__ __launch_bounds__(256) void cast_x_kernel(const float* __restrict__ x,
                                                     ushort* __restrict__ xb) {
  const int i = blockIdx.x * 256 + threadIdx.x;
  const float4 v0 = reinterpret_cast<const float4*>(x)[2 * i];
  const float4 v1 = reinterpret_cast<const float4*>(x)[2 * i + 1];
  uint4 o;
  o.x = (unsigned)f2bs(v0.x) | ((unsigned)f2bs(v0.y) << 16);
  o.y = (unsigned)f2bs(v0.z) | ((unsigned)f2bs(v0.w) << 16);
  o.z = (unsigned)f2bs(v1.x) | ((unsigned)f2bs(v1.y) << 16);
  o.w = (unsigned)f2bs(v1.z) | ((unsigned)f2bs(v1.w) << 16);
  reinterpret_cast<uint4*>(xb)[i] = o;
}

// ---- prep: transpose + cast weights: W1t[n][k], W2t[o][k] ----
__global__ __launch_bounds__(256) void prep_w_kernel(const float* __restrict__ W1,
                                                     const float* __restrict__ W2,
                                                     ushort* __restrict__ W1t,
                                                     ushort* __restrict__ W2t) {
  const int i = blockIdx.x * 256 + threadIdx.x;
  if (i < HIDDEN_C * CAT_DIM_C) {
    const int n = i >> 8, k = i & 255;
    W1t[i] = f2bs(W1[k * HIDDEN_C + n]);
  } else {
    const int j = i - HIDDEN_C * CAT_DIM_C;
    const int o = j >> 8, k = j & 255;
    W2t[j] = f2bs(W2[k * OUT_DIM_C + o]);
  }
}

// ---- main fused kernel, pipelined over TPB_TILES tiles ----
// 256 thr / 4 waves. Wave w: GEMM1 cols [w*64,(w+1)*64), GEMM2 edges [w*16,(w+1)*16).
template <int USE_XB>
__global__ __launch_bounds__(256, 3) void edge_ffn_kernel(
    const ushort* __restrict__ xb, const float* __restrict__ xf,
    const int* __restrict__ ei,
    const ushort* __restrict__ W1t, const float* __restrict__ b1,
    const ushort* __restrict__ W2t, const float* __restrict__ b2,
    float* __restrict__ out) {
  __shared__ ushort A[BM * LDA];   // 33,792 B; reused for H after GEMM1

  const int tid  = threadIdx.x;
  const int lane = tid & 63;
  const int w    = tid >> 6;
  const int l15  = lane & 15;
  const int lg   = lane >> 4;
  const int li   = tid & 15;        // staging: 16 lanes cover one 128-elem half-row
  const int hr0  = tid >> 4;        // staging half-row base
  const int tile0 = blockIdx.x * TPB_TILES;

  float b1v[4], b2v[4];
#pragma unroll
  for (int n = 0; n < 4; ++n) {
    b1v[n] = b1[w * 64 + n * 16 + l15];
    b2v[n] = b2[n * 16 + l15];
  }

  int   nid[8];
  uint4 rbuf[8];

#define LOAD_NID(tt)                                                        \
  {                                                                         \
    const int e0n = (tt) * BM;                                              \
    _Pragma("unroll") for (int it = 0; it < 8; ++it) {                      \
      const int hr = hr0 + it * 16;                                         \
      nid[it] = ei[(hr & 1) * N_EDGES_C + e0n + (hr >> 1)];                 \
    }                                                                       \
  }

#define GATHER()                                                            \
  {                                                                         \
    _Pragma("unroll") for (int it = 0; it < 8; ++it) {                      \
      if (USE_XB) {                                                         \
        rbuf[it] = *reinterpret_cast<const uint4*>(                         \
            xb + (size_t)nid[it] * IN_DIM_C + li * 8);                      \
      } else {                                                              \
        const float4* row =                                                 \
            reinterpret_cast<const float4*>(xf + (size_t)nid[it] * IN_DIM_C);\
        const float4 v0 = row[li * 2];                                      \
        const float4 v1 = row[li * 2 + 1];                                  \
        uint4 o;                                                            \
        o.x = (unsigned)f2bs(v0.x) | ((unsigned)f2bs(v0.y) << 16);          \
        o.y = (unsigned)f2bs(v0.z) | ((unsigned)f2bs(v0.w) << 16);          \
        o.z = (unsigned)f2bs(v1.x) | ((unsigned)f2bs(v1.y) << 16);          \
        o.w = (unsigned)f2bs(v1.z) | ((unsigned)f2bs(v1.w) << 16);          \
        rbuf[it] = o;                                                       \
      }                                                                     \
    }                                                                       \
  }

  // --- prologue: fill pipeline ---
  LOAD_NID(tile0);
  GATHER();                 // tile 0 rows -> rbuf
  LOAD_NID(tile0 + 1);      // indices for tile 1

  for (int t = 0; t < TPB_TILES; ++t) {
    const int e0 = (tile0 + t) * BM;

    __syncthreads();        // prev GEMM2 done reading A/H region
    // ---------- stage tile t from registers into LDS ----------
#pragma unroll
    for (int it = 0; it < 8; ++it) {
      const int hr = hr0 + it * 16;
      *reinterpret_cast<uint4*>(&A[(hr >> 1) * LDA + (hr & 1) * IN_DIM_C + li * 8]) =
          rbuf[it];
    }
    __syncthreads();        // A ready

    // ---------- GEMM1: h[64 x 256] = A @ W1 ----------
    f32x4 acc[4][4];
#pragma unroll
    for (int m = 0; m < 4; ++m)
#pragma unroll
      for (int n = 0; n < 4; ++n) acc[m][n] = (f32x4){0.f, 0.f, 0.f, 0.f};

#pragma unroll
    for (int ks = 0; ks < 8; ++ks) {
      const int kb = ks * 32 + lg * 8;
      bf16x8 a[4], b[4];
#pragma unroll
      for (int m = 0; m < 4; ++m)
        a[m] = *reinterpret_cast<const bf16x8*>(&A[(m * 16 + l15) * LDA + kb]);
#pragma unroll
      for (int n = 0; n < 4; ++n)
        b[n] = *reinterpret_cast<const bf16x8*>(W1t + (w * 64 + n * 16 + l15) * CAT_DIM_C + kb);
#pragma unroll
      for (int m = 0; m < 4; ++m)
#pragma unroll
        for (int n = 0; n < 4; ++n)
          acc[m][n] = __builtin_amdgcn_mfma_f32_16x16x32_bf16(a[m], b[n], acc[m][n], 0, 0, 0);
    }

    // ---------- issue next tile's gather NOW (hidden under H + GEMM2) ----------
    if (t + 1 < TPB_TILES) GATHER();
    if (t + 2 < TPB_TILES) LOAD_NID(tile0 + t + 2);

    __syncthreads();        // all waves done reading A before overwrite with H

    // ---------- bias + relu, h -> bf16 into LDS (reuse A) ----------
#pragma unroll
    for (int m = 0; m < 4; ++m)
#pragma unroll
      for (int n = 0; n < 4; ++n)
#pragma unroll
        for (int i = 0; i < 4; ++i) {
          float v = acc[m][n][i] + b1v[n];
          v = v > 0.f ? v : 0.f;
          A[(m * 16 + lg * 4 + i) * LDA + w * 64 + n * 16 + l15] = f2bs(v);
        }
    __syncthreads();        // H visible

    // ---------- GEMM2: out[64 x 64] = H @ W2 ----------
    f32x4 acc2[4];
#pragma unroll
    for (int n = 0; n < 4; ++n) acc2[n] = (f32x4){0.f, 0.f, 0.f, 0.f};

#pragma unroll
    for (int ks = 0; ks < 8; ++ks) {
      const int kb = ks * 32 + lg * 8;
      const bf16x8 a2 = *reinterpret_cast<const bf16x8*>(&A[(w * 16 + l15) * LDA + kb]);
#pragma unroll
      for (int n = 0; n < 4; ++n) {
        const bf16x8 bb =
            *reinterpret_cast<const bf16x8*>(W2t + (n * 16 + l15) * HIDDEN_C + kb);
        acc2[n] = __builtin_amdgcn_mfma_f32_16x16x32_bf16(a2, bb, acc2[n], 0, 0, 0);
      }
    }

    // ---------- epilogue: + b2, store f32 ----------
#pragma unroll
    for (int n = 0; n < 4; ++n)
#pragma unroll
      for (int i = 0; i < 4; ++i)
        out[(size_t)(e0 + w * 16 + lg * 4 + i) * OUT_DIM_C + n * 16 + l15] =
            acc2[n][i] + b2v[n];
  }
#undef LOAD_NID
#undef GATHER
}

extern "C" void kernel_launch(void* const* d_in, const int* in_sizes, int n_in,
                              void* d_out, int out_size, void* d_ws, size_t ws_size,
                              hipStream_t stream) {
  const float* x  = (const float*)d_in[0];
  const int*   ei = (const int*)d_in[1];
  const float* W1 = (const float*)d_in[2];
  const float* b1 = (const float*)d_in[3];
  const float* W2 = (const float*)d_in[4];
  const float* b2 = (const float*)d_in[5];
  float* out = (float*)d_out;

  const size_t xb_elems  = (size_t)N_NODES_C * IN_DIM_C;   // 12.8M bf16
  const size_t w1t_elems = HIDDEN_C * CAT_DIM_C;
  const size_t w2t_elems = OUT_DIM_C * HIDDEN_C;
  const size_t need_full = (xb_elems + w1t_elems + w2t_elems) * sizeof(ushort);

  ushort* base = (ushort*)d_ws;
  if (ws_size >= need_full) {
    ushort* xbp = base;
    ushort* W1t = xbp + xb_elems;
    ushort* W2t = W1t + w1t_elems;
    cast_x_kernel<<<(N_NODES_C * IN_DIM_C) / (256 * 8), 256, 0, stream>>>(x, xbp);
    prep_w_kernel<<<(HIDDEN_C * CAT_DIM_C + OUT_DIM_C * HIDDEN_C) / 256, 256, 0, stream>>>(
        W1, W2, W1t, W2t);
    edge_ffn_kernel<1><<<GRID_MAIN, 256, 0, stream>>>(xbp, x, ei, W1t, b1, W2t, b2, out);
  } else {
    ushort* W1t = base;
    ushort* W2t = W1t + w1t_elems;
    prep_w_kernel<<<(HIDDEN_C * CAT_DIM_C + OUT_DIM_C * HIDDEN_C) / 256, 256, 0, stream>>>(
        W1, W2, W1t, W2t);
    edge_ffn_kernel<0><<<GRID_MAIN, 256, 0, stream>>>(nullptr, x, ei, W1t, b1, W2t, b2, out);
  }
}

// Round 5
// 627.756 us; speedup vs baseline: 1.6039x; 1.6039x over previous
//
#include <hip/hip_runtime.h>
#include <hip/hip_bf16.h>

// EdgeFFN: out[e] = relu(concat(x[src[e]], x[dst[e]]) @ W1 + b1) @ W2 + b2
// E=640000, IN=128, CAT=256, HID=256, OUT=64
//
// Round-5 design: BARRIER-FREE swapped-operand formulation.
//  - GEMM1 swapped: H^T[c][e] = sum_k W1t[c][k] * cat[e][k].
//    mfma arg0 (row-operand) = W1t fragment (contiguous 16B from W1t[c][k]),
//    mfma arg1 (col-operand) = gathered x fragment: lane l15 -> its own edge,
//    lg -> k-chunk. The random gather loads DIRECTLY into MFMA operand regs:
//    no LDS staging, no staging registers, no barriers.
//  - GEMM2 swapped+interleaved: per 32-hidden-col block nb, H window (32e x 32c
//    bf16 = 2KB) goes through a per-wave double-buffered LDS window, consumed
//    immediately: out^T += W2t[:, nb-block] @ Hwin. acc1 live = 4 frags only.
//  - Each wave owns 32 edges, fully independent: ZERO __syncthreads.
//    Compiler orders the wave-private LDS write->read via lgkmcnt.
//  - Register-pressure lesson (rounds 2/4 spilled): steady live ~160 regs,
//    launch_bounds(256,2) permissive cap 256. No long-lived staging regs.

#define N_EDGES_C 640000
#define N_NODES_C 100000
#define IN_DIM_C  128
#define CAT_DIM_C 256
#define HIDDEN_C  256
#define OUT_DIM_C 64
#define EPB       128    // edges per block (4 waves x 32)
#define GRID_MAIN (N_EDGES_C / EPB)   // 5000 exactly

typedef __attribute__((ext_vector_type(8))) short bf16x8;
typedef __attribute__((ext_vector_type(4))) float f32x4;

__device__ __forceinline__ ushort f2bs(float f) {
  union { __hip_bfloat16 h; ushort u; } c;
  c.h = __float2bfloat16(f);
  return c.u;
}

// ---- prep: cast node features f32 -> bf16 (vectorized 8/thread) ----
__global__ __launch_bounds__(256) void cast_x_kernel(const float* __restrict__ x,
                                                     ushort* __restrict__ xb) {
  const int i = blockIdx.x * 256 + threadIdx.x;
  const float4 v0 = reinterpret_cast<const float4*>(x)[2 * i];
  const float4 v1 = reinterpret_cast<const float4*>(x)[2 * i + 1];
  uint4 o;
  o.x = (unsigned)f2bs(v0.x) | ((unsigned)f2bs(v0.y) << 16);
  o.y = (unsigned)f2bs(v0.z) | ((unsigned)f2bs(v0.w) << 16);
  o.z = (unsigned)f2bs(v1.x) | ((unsigned)f2bs(v1.y) << 16);
  o.w = (unsigned)f2bs(v1.z) | ((unsigned)f2bs(v1.w) << 16);
  reinterpret_cast<uint4*>(xb)[i] = o;
}

// ---- prep: transpose + cast weights: W1t[c][k] = W1[k][c], W2t[o][k] = W2[k][o] ----
__global__ __launch_bounds__(256) void prep_w_kernel(const float* __restrict__ W1,
                                                     const float* __restrict__ W2,
                                                     ushort* __restrict__ W1t,
                                                     ushort* __restrict__ W2t) {
  const int i = blockIdx.x * 256 + threadIdx.x;
  if (i < HIDDEN_C * CAT_DIM_C) {
    const int n = i >> 8, k = i & 255;
    W1t[i] = f2bs(W1[k * HIDDEN_C + n]);
  } else {
    const int j = i - HIDDEN_C * CAT_DIM_C;
    const int o = j >> 8, k = j & 255;
    W2t[j] = f2bs(W2[k * OUT_DIM_C + o]);
  }
}

// ---- main fused kernel: barrier-free, one 128-edge tile per block ----
template <int USE_XB>
__global__ __launch_bounds__(256, 2) void edge_ffn_kernel(
    const ushort* __restrict__ xb, const float* __restrict__ xf,
    const int* __restrict__ ei,
    const ushort* __restrict__ W1t, const float* __restrict__ b1,
    const ushort* __restrict__ W2t, const float* __restrict__ b2,
    float* __restrict__ out) {
  // per-wave double-buffered H window: [wave][dbuf][32 edges][40 cols pad]
  // row stride 80B: 16B-aligned for b128 reads; bank spread = b64/b128 BW floor.
  __shared__ ushort Hw[4][2][32][40];

  const int tid = threadIdx.x;
  const int l15 = tid & 15;
  const int lg  = (tid >> 4) & 3;
  const int wv  = tid >> 6;
  const int e_base = blockIdx.x * EPB + wv * 32;

  // ---- per-lane node ids (lane l15 owns edges e_base + ef*16 + l15) ----
  int ns[2], nd[2];
#pragma unroll
  for (int ef = 0; ef < 2; ++ef) {
    const int e = e_base + ef * 16 + l15;
    ns[ef] = ei[e];
    nd[ef] = ei[N_EDGES_C + e];
  }

  // ---- gather x fragments straight into MFMA B-operand registers ----
  // frag (ef, ks): lane reads cat[e][ks*32 + lg*8 .. +8]; k<128 -> src row, else dst.
  bf16x8 xfr[2][8];
#pragma unroll
  for (int ef = 0; ef < 2; ++ef) {
#pragma unroll
    for (int ks = 0; ks < 8; ++ks) {
      const int node = (ks < 4) ? ns[ef] : nd[ef];
      const int koff = (ks & 3) * 32 + lg * 8;
      if (USE_XB) {
        xfr[ef][ks] = *reinterpret_cast<const bf16x8*>(
            xb + (size_t)node * IN_DIM_C + koff);
      } else {
        const float4* row = reinterpret_cast<const float4*>(
            xf + (size_t)node * IN_DIM_C + koff);
        const float4 v0 = row[0];
        const float4 v1 = row[1];
        uint4 o;
        o.x = (unsigned)f2bs(v0.x) | ((unsigned)f2bs(v0.y) << 16);
        o.y = (unsigned)f2bs(v0.z) | ((unsigned)f2bs(v0.w) << 16);
        o.z = (unsigned)f2bs(v1.x) | ((unsigned)f2bs(v1.y) << 16);
        o.w = (unsigned)f2bs(v1.z) | ((unsigned)f2bs(v1.w) << 16);
        xfr[ef][ks] = *reinterpret_cast<const bf16x8*>(&o);
      }
    }
  }

  // ---- out bias fragments: o = of*16 + lg*4 + i ----
  f32x4 b2v[4];
#pragma unroll
  for (int of = 0; of < 4; ++of)
    b2v[of] = *reinterpret_cast<const f32x4*>(b2 + of * 16 + lg * 4);

  // ---- GEMM2 accumulators: out^T, rows o (4 frags), cols e (2 frags) ----
  f32x4 acc2[4][2];
#pragma unroll
  for (int of = 0; of < 4; ++of)
#pragma unroll
    for (int ef = 0; ef < 2; ++ef) acc2[of][ef] = (f32x4){0.f, 0.f, 0.f, 0.f};

  // ---- main loop over hidden 32-col blocks ----
#pragma unroll
  for (int nb = 0; nb < 8; ++nb) {
    // GEMM1 (swapped): acc1[np][ef] = H^T tile, rows c = nb*32+np*16+lg*4+i,
    // cols e = ef*16+l15 (C-layout: col=lane&15, row=(lane>>4)*4+reg).
    f32x4 acc1[2][2];
#pragma unroll
    for (int np = 0; np < 2; ++np)
#pragma unroll
      for (int ef = 0; ef < 2; ++ef) acc1[np][ef] = (f32x4){0.f, 0.f, 0.f, 0.f};

#pragma unroll
    for (int np = 0; np < 2; ++np) {
      const ushort* wrow = W1t + (size_t)(nb * 32 + np * 16 + l15) * CAT_DIM_C + lg * 8;
#pragma unroll
      for (int ks = 0; ks < 8; ++ks) {
        const bf16x8 wf = *reinterpret_cast<const bf16x8*>(wrow + ks * 32);
        acc1[np][0] = __builtin_amdgcn_mfma_f32_16x16x32_bf16(wf, xfr[0][ks], acc1[np][0], 0, 0, 0);
        acc1[np][1] = __builtin_amdgcn_mfma_f32_16x16x32_bf16(wf, xfr[1][ks], acc1[np][1], 0, 0, 0);
      }
    }

    // bias + relu -> bf16, write H window (lane's 4 consecutive c per frag: b64)
#pragma unroll
    for (int np = 0; np < 2; ++np) {
      const f32x4 b1q = *reinterpret_cast<const f32x4*>(b1 + nb * 32 + np * 16 + lg * 4);
#pragma unroll
      for (int ef = 0; ef < 2; ++ef) {
        float v0 = acc1[np][ef][0] + b1q[0];
        float v1 = acc1[np][ef][1] + b1q[1];
        float v2 = acc1[np][ef][2] + b1q[2];
        float v3 = acc1[np][ef][3] + b1q[3];
        v0 = v0 > 0.f ? v0 : 0.f;
        v1 = v1 > 0.f ? v1 : 0.f;
        v2 = v2 > 0.f ? v2 : 0.f;
        v3 = v3 > 0.f ? v3 : 0.f;
        uint2 u;
        u.x = (unsigned)f2bs(v0) | ((unsigned)f2bs(v1) << 16);
        u.y = (unsigned)f2bs(v2) | ((unsigned)f2bs(v3) << 16);
        *reinterpret_cast<uint2*>(&Hw[wv][nb & 1][ef * 16 + l15][np * 16 + lg * 4]) = u;
      }
    }

    // GEMM2 partial (swapped): acc2 += W2t[:, nb*32..+32] @ Hwin
    // (compiler inserts lgkmcnt wait between the wave's LDS writes and reads)
    bf16x8 hfrag[2];
#pragma unroll
    for (int ef = 0; ef < 2; ++ef)
      hfrag[ef] = *reinterpret_cast<const bf16x8*>(&Hw[wv][nb & 1][ef * 16 + l15][lg * 8]);
#pragma unroll
    for (int of = 0; of < 4; ++of) {
      const bf16x8 w2f = *reinterpret_cast<const bf16x8*>(
          W2t + (size_t)(of * 16 + l15) * HIDDEN_C + nb * 32 + lg * 8);
#pragma unroll
      for (int ef = 0; ef < 2; ++ef)
        acc2[of][ef] = __builtin_amdgcn_mfma_f32_16x16x32_bf16(w2f, hfrag[ef], acc2[of][ef], 0, 0, 0);
    }
  }

  // ---- epilogue: out[e][o] = acc2^T + b2 ; 16B f32x4 stores ----
#pragma unroll
  for (int ef = 0; ef < 2; ++ef) {
    const size_t erow = (size_t)(e_base + ef * 16 + l15) * OUT_DIM_C;
#pragma unroll
    for (int of = 0; of < 4; ++of) {
      f32x4 v;
      v[0] = acc2[of][ef][0] + b2v[of][0];
      v[1] = acc2[of][ef][1] + b2v[of][1];
      v[2] = acc2[of][ef][2] + b2v[of][2];
      v[3] = acc2[of][ef][3] + b2v[of][3];
      *reinterpret_cast<f32x4*>(out + erow + of * 16 + lg * 4) = v;
    }
  }
}

extern "C" void kernel_launch(void* const* d_in, const int* in_sizes, int n_in,
                              void* d_out, int out_size, void* d_ws, size_t ws_size,
                              hipStream_t stream) {
  const float* x  = (const float*)d_in[0];
  const int*   ei = (const int*)d_in[1];
  const float* W1 = (const float*)d_in[2];
  const float* b1 = (const float*)d_in[3];
  const float* W2 = (const float*)d_in[4];
  const float* b2 = (const float*)d_in[5];
  float* out = (float*)d_out;

  const size_t xb_elems  = (size_t)N_NODES_C * IN_DIM_C;   // 12.8M bf16
  const size_t w1t_elems = HIDDEN_C * CAT_DIM_C;
  const size_t w2t_elems = OUT_DIM_C * HIDDEN_C;
  const size_t need_full = (xb_elems + w1t_elems + w2t_elems) * sizeof(ushort);

  ushort* base = (ushort*)d_ws;
  if (ws_size >= need_full) {
    ushort* xbp = base;
    ushort* W1t = xbp + xb_elems;
    ushort* W2t = W1t + w1t_elems;
    cast_x_kernel<<<(N_NODES_C * IN_DIM_C) / (256 * 8), 256, 0, stream>>>(x, xbp);
    prep_w_kernel<<<(HIDDEN_C * CAT_DIM_C + OUT_DIM_C * HIDDEN_C) / 256, 256, 0, stream>>>(
        W1, W2, W1t, W2t);
    edge_ffn_kernel<1><<<GRID_MAIN, 256, 0, stream>>>(xbp, x, ei, W1t, b1, W2t, b2, out);
  } else {
    ushort* W1t = base;
    ushort* W2t = W1t + w1t_elems;
    prep_w_kernel<<<(HIDDEN_C * CAT_DIM_C + OUT_DIM_C * HIDDEN_C) / 256, 256, 0, stream>>>(
        W1, W2, W1t, W2t);
    edge_ffn_kernel<0><<<GRID_MAIN, 256, 0, stream>>>(nullptr, x, ei, W1t, b1, W2t, b2, out);
  }
}

// Round 6
// 606.654 us; speedup vs baseline: 1.6597x; 1.0348x over previous
//
#include <hip/hip_runtime.h>
#include <hip/hip_bf16.h>

// EdgeFFN: out[e] = relu(concat(x[src[e]], x[dst[e]]) @ W1 + b1) @ W2 + b2
// E=640000, IN=128, CAT=256, HID=256, OUT=64
//
// Round-6: barrier-free swapped-operand skeleton (round-5, passed clean) plus:
//  - Fragment-PACKED weights W1p/W2p: each MFMA A-fragment is a contiguous
//    1 KB block (addr = blk*1024 + lane*16) -> 4-line coalesced W-loads
//    (round-5 layout touched 16 lines/load: 512B row stride across l15 lanes).
//  - Nontemporal out stores: keep xb L3-resident (round-5 FETCH 150 MB = out
//    stream thrashed L3, gathers fell through to HBM).
//  - launch_bounds(256,4): round-5 natural allocation = 76 VGPR + 48 acc = 124
//    <= 128 cap -> 4 waves/SIMD without spill. Spill gate = WRITE_SIZE.
//  - s_setprio(1) around MFMA clusters (T5; independent-wave regime).

#define N_EDGES_C 640000
#define N_NODES_C 100000
#define IN_DIM_C  128
#define CAT_DIM_C 256
#define HIDDEN_C  256
#define OUT_DIM_C 64
#define EPB       128    // edges per block (4 waves x 32)
#define GRID_MAIN (N_EDGES_C / EPB)   // 5000 exactly

typedef __attribute__((ext_vector_type(8))) short bf16x8;
typedef __attribute__((ext_vector_type(4))) float f32x4;

__device__ __forceinline__ ushort f2bs(float f) {
  union { __hip_bfloat16 h; ushort u; } c;
  c.h = __float2bfloat16(f);
  return c.u;
}

// ---- prep: cast node features f32 -> bf16 (vectorized 8/thread) ----
__global__ __launch_bounds__(256) void cast_x_kernel(const float* __restrict__ x,
                                                     ushort* __restrict__ xb) {
  const int i = blockIdx.x * 256 + threadIdx.x;
  const float4 v0 = reinterpret_cast<const float4*>(x)[2 * i];
  const float4 v1 = reinterpret_cast<const float4*>(x)[2 * i + 1];
  uint4 o;
  o.x = (unsigned)f2bs(v0.x) | ((unsigned)f2bs(v0.y) << 16);
  o.y = (unsigned)f2bs(v0.z) | ((unsigned)f2bs(v0.w) << 16);
  o.z = (unsigned)f2bs(v1.x) | ((unsigned)f2bs(v1.y) << 16);
  o.w = (unsigned)f2bs(v1.z) | ((unsigned)f2bs(v1.w) << 16);
  reinterpret_cast<uint4*>(xb)[i] = o;
}

// ---- prep: fragment-packed weights ----
// W1p: for (nb,np,ks) block b=(nb*2+np)*8+ks, lane l, elem e:
//   W1p[b*512 + l*8 + e] = W1t[row = nb*32+np*16+(l&15)][k = ks*32+(l>>4)*8+e]
//                        = W1[k][row]
// W2p: block b=of*8+nb: W2p[b*512 + l*8 + e] = W2[k = nb*32+(l>>4)*8+e][o = of*16+(l&15)]
__global__ __launch_bounds__(256) void prep_w_kernel(const float* __restrict__ W1,
                                                     const float* __restrict__ W2,
                                                     ushort* __restrict__ W1p,
                                                     ushort* __restrict__ W2p) {
  const int i = blockIdx.x * 256 + threadIdx.x;   // 320 blocks
  if (i < HIDDEN_C * CAT_DIM_C) {
    const int e = i & 7, lane = (i >> 3) & 63, blk = i >> 9;
    const int ks = blk & 7, np = (blk >> 3) & 1, nb = blk >> 4;
    const int row = nb * 32 + np * 16 + (lane & 15);
    const int k   = ks * 32 + (lane >> 4) * 8 + e;
    W1p[i] = f2bs(W1[k * HIDDEN_C + row]);
  } else {
    const int j = i - HIDDEN_C * CAT_DIM_C;
    const int e = j & 7, lane = (j >> 3) & 63, blk = j >> 9;
    const int nb = blk & 7, of = blk >> 3;
    const int o = of * 16 + (lane & 15);
    const int k = nb * 32 + (lane >> 4) * 8 + e;
    W2p[j] = f2bs(W2[k * OUT_DIM_C + o]);
  }
}

// ---- main fused kernel: barrier-free, one 128-edge tile per block ----
template <int USE_XB>
__global__ __launch_bounds__(256, 4) void edge_ffn_kernel(
    const ushort* __restrict__ xb, const float* __restrict__ xf,
    const int* __restrict__ ei,
    const ushort* __restrict__ W1p, const float* __restrict__ b1,
    const ushort* __restrict__ W2p, const float* __restrict__ b2,
    float* __restrict__ out) {
  // per-wave double-buffered H window: [wave][dbuf][32 edges][40 cols pad]
  __shared__ ushort Hw[4][2][32][40];

  const int tid = threadIdx.x;
  const int l   = tid & 63;
  const int l15 = tid & 15;
  const int lg  = (tid >> 4) & 3;
  const int wv  = tid >> 6;
  const int e_base = blockIdx.x * EPB + wv * 32;

  // ---- per-lane node ids (lane l15 owns edges e_base + ef*16 + l15) ----
  int ns[2], nd[2];
#pragma unroll
  for (int ef = 0; ef < 2; ++ef) {
    const int e = e_base + ef * 16 + l15;
    ns[ef] = ei[e];
    nd[ef] = ei[N_EDGES_C + e];
  }

  // ---- gather x fragments straight into MFMA B-operand registers ----
  bf16x8 xfr[2][8];
#pragma unroll
  for (int ef = 0; ef < 2; ++ef) {
#pragma unroll
    for (int ks = 0; ks < 8; ++ks) {
      const int node = (ks < 4) ? ns[ef] : nd[ef];
      const int koff = (ks & 3) * 32 + lg * 8;
      if (USE_XB) {
        xfr[ef][ks] = *reinterpret_cast<const bf16x8*>(
            xb + (size_t)node * IN_DIM_C + koff);
      } else {
        const float4* row = reinterpret_cast<const float4*>(
            xf + (size_t)node * IN_DIM_C + koff);
        const float4 v0 = row[0];
        const float4 v1 = row[1];
        uint4 o;
        o.x = (unsigned)f2bs(v0.x) | ((unsigned)f2bs(v0.y) << 16);
        o.y = (unsigned)f2bs(v0.z) | ((unsigned)f2bs(v0.w) << 16);
        o.z = (unsigned)f2bs(v1.x) | ((unsigned)f2bs(v1.y) << 16);
        o.w = (unsigned)f2bs(v1.z) | ((unsigned)f2bs(v1.w) << 16);
        xfr[ef][ks] = *reinterpret_cast<const bf16x8*>(&o);
      }
    }
  }

  // ---- GEMM2 accumulators: out^T, rows o (4 frags), cols e (2 frags) ----
  f32x4 acc2[4][2];
#pragma unroll
  for (int of = 0; of < 4; ++of)
#pragma unroll
    for (int ef = 0; ef < 2; ++ef) acc2[of][ef] = (f32x4){0.f, 0.f, 0.f, 0.f};

  // ---- main loop over hidden 32-col blocks ----
#pragma unroll
  for (int nb = 0; nb < 8; ++nb) {
    f32x4 acc1[2][2];
#pragma unroll
    for (int np = 0; np < 2; ++np)
#pragma unroll
      for (int ef = 0; ef < 2; ++ef) acc1[np][ef] = (f32x4){0.f, 0.f, 0.f, 0.f};

    __builtin_amdgcn_s_setprio(1);
#pragma unroll
    for (int np = 0; np < 2; ++np) {
      const ushort* wbase = W1p + (size_t)(((nb * 2 + np) * 8) * 64 + l) * 8;
#pragma unroll
      for (int ks = 0; ks < 8; ++ks) {
        const bf16x8 wf = *reinterpret_cast<const bf16x8*>(wbase + (size_t)ks * 512);
        acc1[np][0] = __builtin_amdgcn_mfma_f32_16x16x32_bf16(wf, xfr[0][ks], acc1[np][0], 0, 0, 0);
        acc1[np][1] = __builtin_amdgcn_mfma_f32_16x16x32_bf16(wf, xfr[1][ks], acc1[np][1], 0, 0, 0);
      }
    }
    __builtin_amdgcn_s_setprio(0);

    // bias + relu -> bf16, write H window
#pragma unroll
    for (int np = 0; np < 2; ++np) {
      const f32x4 b1q = *reinterpret_cast<const f32x4*>(b1 + nb * 32 + np * 16 + lg * 4);
#pragma unroll
      for (int ef = 0; ef < 2; ++ef) {
        float v0 = acc1[np][ef][0] + b1q[0];
        float v1 = acc1[np][ef][1] + b1q[1];
        float v2 = acc1[np][ef][2] + b1q[2];
        float v3 = acc1[np][ef][3] + b1q[3];
        v0 = v0 > 0.f ? v0 : 0.f;
        v1 = v1 > 0.f ? v1 : 0.f;
        v2 = v2 > 0.f ? v2 : 0.f;
        v3 = v3 > 0.f ? v3 : 0.f;
        uint2 u;
        u.x = (unsigned)f2bs(v0) | ((unsigned)f2bs(v1) << 16);
        u.y = (unsigned)f2bs(v2) | ((unsigned)f2bs(v3) << 16);
        *reinterpret_cast<uint2*>(&Hw[wv][nb & 1][ef * 16 + l15][np * 16 + lg * 4]) = u;
      }
    }

    // GEMM2 partial: acc2 += W2p-frag @ Hwin (wave-private LDS, lgkmcnt-ordered)
    bf16x8 hfrag[2];
#pragma unroll
    for (int ef = 0; ef < 2; ++ef)
      hfrag[ef] = *reinterpret_cast<const bf16x8*>(&Hw[wv][nb & 1][ef * 16 + l15][lg * 8]);
    __builtin_amdgcn_s_setprio(1);
#pragma unroll
    for (int of = 0; of < 4; ++of) {
      const bf16x8 w2f = *reinterpret_cast<const bf16x8*>(
          W2p + (size_t)((of * 8 + nb) * 64 + l) * 8);
#pragma unroll
      for (int ef = 0; ef < 2; ++ef)
        acc2[of][ef] = __builtin_amdgcn_mfma_f32_16x16x32_bf16(w2f, hfrag[ef], acc2[of][ef], 0, 0, 0);
    }
    __builtin_amdgcn_s_setprio(0);
  }

  // ---- epilogue: out[e][o] = acc2^T + b2 ; nontemporal 16B stores ----
#pragma unroll
  for (int ef = 0; ef < 2; ++ef) {
    const size_t erow = (size_t)(e_base + ef * 16 + l15) * OUT_DIM_C;
#pragma unroll
    for (int of = 0; of < 4; ++of) {
      const f32x4 b2q = *reinterpret_cast<const f32x4*>(b2 + of * 16 + lg * 4);
      f32x4 v;
      v[0] = acc2[of][ef][0] + b2q[0];
      v[1] = acc2[of][ef][1] + b2q[1];
      v[2] = acc2[of][ef][2] + b2q[2];
      v[3] = acc2[of][ef][3] + b2q[3];
      __builtin_nontemporal_store(v, reinterpret_cast<f32x4*>(out + erow + of * 16 + lg * 4));
    }
  }
}

extern "C" void kernel_launch(void* const* d_in, const int* in_sizes, int n_in,
                              void* d_out, int out_size, void* d_ws, size_t ws_size,
                              hipStream_t stream) {
  const float* x  = (const float*)d_in[0];
  const int*   ei = (const int*)d_in[1];
  const float* W1 = (const float*)d_in[2];
  const float* b1 = (const float*)d_in[3];
  const float* W2 = (const float*)d_in[4];
  const float* b2 = (const float*)d_in[5];
  float* out = (float*)d_out;

  const size_t xb_elems  = (size_t)N_NODES_C * IN_DIM_C;   // 12.8M bf16
  const size_t w1p_elems = HIDDEN_C * CAT_DIM_C;
  const size_t w2p_elems = OUT_DIM_C * HIDDEN_C;
  const size_t need_full = (xb_elems + w1p_elems + w2p_elems) * sizeof(ushort);

  ushort* base = (ushort*)d_ws;
  if (ws_size >= need_full) {
    ushort* xbp = base;
    ushort* W1p = xbp + xb_elems;
    ushort* W2p = W1p + w1p_elems;
    cast_x_kernel<<<(N_NODES_C * IN_DIM_C) / (256 * 8), 256, 0, stream>>>(x, xbp);
    prep_w_kernel<<<(HIDDEN_C * CAT_DIM_C + OUT_DIM_C * HIDDEN_C) / 256, 256, 0, stream>>>(
        W1, W2, W1p, W2p);
    edge_ffn_kernel<1><<<GRID_MAIN, 256, 0, stream>>>(xbp, x, ei, W1p, b1, W2p, b2, out);
  } else {
    ushort* W1p = base;
    ushort* W2p = W1p + w1p_elems;
    prep_w_kernel<<<(HIDDEN_C * CAT_DIM_C + OUT_DIM_C * HIDDEN_C) / 256, 256, 0, stream>>>(
        W1, W2, W1p, W2p);
    edge_ffn_kernel<0><<<GRID_MAIN, 256, 0, stream>>>(nullptr, x, ei, W1p, b1, W2p, b2, out);
  }
}